// Round 5
// baseline (692.776 us; speedup 1.0000x reference)
//
#include <hip/hip_runtime.h>
#include <hip/hip_bf16.h>
#include <math.h>

#define NTOK   65536
#define L_SEQ  16384

typedef __bf16 bf16_t;
typedef bf16_t bf16x8 __attribute__((ext_vector_type(8)));
typedef bf16_t bf16x4 __attribute__((ext_vector_type(4)));
typedef float  f32x4  __attribute__((ext_vector_type(4)));

__device__ inline float phi_f(float x) { return x > 0.f ? x + 1.f : __expf(x); }

__device__ inline float quad_sum(float v) {
    v += __shfl_xor(v, 1);
    v += __shfl_xor(v, 2);
    v += __shfl_xor(v, 4);
    v += __shfl_xor(v, 8);
    return v;
}

__device__ inline float ld_any(const void* p, size_t i, int f32) {
    return f32 ? ((const float*)p)[i] : (float)((const bf16_t*)p)[i];
}

// Fragment-major weight layout: weights stored so one MFMA B-frag is a
// contiguous 1KB block, lane l at +l*16B. For logical W_t[n][k] (n=out col,
// k=in dim), frag id = (n>>4)*KK + (k>>5); within: quad=(k>>3)&3, l15=n&15,
// off=k&7 -> lane = quad*16+l15.
__device__ inline size_t fragmajor(int n, int k, int KK) {
    return ((size_t)((n >> 4) * KK + (k >> 5)) << 9)
         + (size_t)((((k >> 3) & 3) << 7) + ((n & 15) << 3) + (k & 7));
}

// load B-frag (S = n>>4 subtile, kk = k>>5 step) as one coalesced 16B/lane read
__device__ inline bf16x8 ld_frag(const bf16_t* __restrict__ Wf, int S, int kk,
                                 int KK, int lane) {
    return *(const bf16x8*)&Wf[(((size_t)(S * KK + kk)) << 9) + ((size_t)lane << 3)];
}

// ------------------------------------------------- K-1: dtype probe
__global__ __launch_bounds__(256) void k_detect(const void* __restrict__ xraw,
                                                int* __restrict__ flag) {
    __shared__ int bad;
    if (threadIdx.x == 0) bad = 0;
    __syncthreads();
    const bf16_t* xb = (const bf16_t*)xraw;
    int mybad = 0;
#pragma unroll
    for (int j = 0; j < 16; ++j) {
        float v = fabsf((float)xb[threadIdx.x + 256 * j]);
        if (!(v <= 1000.f)) mybad = 1;
    }
    if (mybad) atomicOr(&bad, 1);
    __syncthreads();
    if (threadIdx.x == 0) *flag = bad;
}

// ------------------------------------------------- K0a: x -> canonical bf16
__global__ __launch_bounds__(256) void k_convert(const void* __restrict__ xraw,
                                                 const int* __restrict__ flag,
                                                 bf16_t* __restrict__ xbf) {
    const int f = *flag;
    size_t i = ((size_t)blockIdx.x * 256 + threadIdx.x) * 4;
    if (f) {
        f32x4 v = *(const f32x4*)((const float*)xraw + i);
        bf16x4 o;
#pragma unroll
        for (int j = 0; j < 4; ++j) o[j] = (bf16_t)v[j];
        *(bf16x4*)&xbf[i] = o;
    } else {
        *(bf16x4*)&xbf[i] = *(const bf16x4*)((const bf16_t*)xraw + i);
    }
}

// ------------------------------------------------- K0b: weights -> fragment-major
__global__ __launch_bounds__(256) void k_prep(
    const void* __restrict__ Wq, const void* __restrict__ Wk,
    const void* __restrict__ Wv, const void* __restrict__ Wo,
    const void* __restrict__ W1, const void* __restrict__ W2,
    const void* __restrict__ bq, const void* __restrict__ bk,
    const void* __restrict__ bv, const void* __restrict__ bo,
    const void* __restrict__ b1, const void* __restrict__ b2,
    const void* __restrict__ g1, const void* __restrict__ be1,
    const void* __restrict__ g2, const void* __restrict__ be2,
    const int* __restrict__ flag,
    bf16_t* __restrict__ Wqkv_f, bf16_t* __restrict__ Wo_f,
    bf16_t* __restrict__ W1_f, bf16_t* __restrict__ W2_f,
    bf16_t* __restrict__ pbuf, float* __restrict__ kvbuf) {
    const int f = *flag;
    int idx = blockIdx.x * 256 + threadIdx.x;
    if (idx < 196608) {                       // Wqkv [768 n][256 k], KK=8
        int n = idx >> 8, k = idx & 255;
        float v;
        if (n < 256)      v = ld_any(Wq, k * 256 + n, f);
        else if (n < 512) v = ld_any(Wk, k * 256 + (n - 256), f);
        else              v = ld_any(Wv, k * 256 + (n - 512), f);
        Wqkv_f[fragmajor(n, k, 8)] = (bf16_t)v;
    } else if (idx < 262144) {                // Wo [256][256], KK=8
        int i = idx - 196608; int n = i >> 8, k = i & 255;
        Wo_f[fragmajor(n, k, 8)] = (bf16_t)ld_any(Wo, k * 256 + n, f);
    } else if (idx < 524288) {                // W1 [1024 n][256 k], KK=8
        int i = idx - 262144; int n = i >> 8, k = i & 255;
        W1_f[fragmajor(n, k, 8)] = (bf16_t)ld_any(W1, k * 1024 + n, f);
    } else if (idx < 786432) {                // W2 [256 n][1024 k], KK=32
        int i = idx - 524288; int n = i >> 10, k = i & 1023;
        W2_f[fragmajor(n, k, 32)] = (bf16_t)ld_any(W2, k * 256 + n, f);
    } else if (idx < 820224) {                // KV state zero-init
        kvbuf[idx - 786432] = 0.f;
    } else if (idx < 823552) {                // bias/param pack
        int i = idx - 820224;
        float v;
        if (i < 256)        v = ld_any(bq, i, f);
        else if (i < 512)   v = ld_any(bk, i - 256, f);
        else if (i < 768)   v = ld_any(bv, i - 512, f);
        else if (i < 1024)  v = ld_any(bo, i - 768, f);
        else if (i < 2048)  v = ld_any(b1, i - 1024, f);
        else if (i < 2304)  v = ld_any(b2, i - 2048, f);
        else if (i < 2560)  v = ld_any(g1, i - 2304, f);
        else if (i < 2816)  v = ld_any(be1, i - 2560, f);
        else if (i < 3072)  v = ld_any(g2, i - 2816, f);
        else                v = ld_any(be2, i - 3072, f);
        pbuf[i] = (bf16_t)v;
    }
}

// ------------------------------------------------- K1: QKV GEMM + phi
// grid (512, 6): M=128 (wave owns 2 m-frags), N=128. No LDS, no barriers.
__global__ __launch_bounds__(256, 3) void k_qkv(
    const bf16_t* __restrict__ x, const bf16_t* __restrict__ Wqkv_f,
    const bf16_t* __restrict__ pbuf,
    bf16_t* __restrict__ q_phi, bf16_t* __restrict__ k_phi,
    bf16_t* __restrict__ v_out) {
    const int mt = blockIdx.x, nt = blockIdx.y;
    const int tid = threadIdx.x, wave = tid >> 6, lane = tid & 63;
    const int l15 = lane & 15, quad = lane >> 4, q8 = quad * 8;
    const int rb = mt * 128 + wave * 32;
    f32x4 acc[2][8] = {};
    for (int kk = 0; kk < 8; ++kk) {
        bf16x8 a0 = *(const bf16x8*)&x[(size_t)(rb + l15) * 256 + kk * 32 + q8];
        bf16x8 a1 = *(const bf16x8*)&x[(size_t)(rb + 16 + l15) * 256 + kk * 32 + q8];
#pragma unroll
        for (int s = 0; s < 8; ++s) {
            bf16x8 b = ld_frag(Wqkv_f, nt * 8 + s, kk, 8, lane);
            acc[0][s] = __builtin_amdgcn_mfma_f32_16x16x32_bf16(a0, b, acc[0][s], 0, 0, 0);
            acc[1][s] = __builtin_amdgcn_mfma_f32_16x16x32_bf16(a1, b, acc[1][s], 0, 0, 0);
        }
    }
#pragma unroll
    for (int s = 0; s < 8; ++s) {
        int ng = nt * 128 + s * 16 + l15;
        bf16_t* dst = ng < 256 ? q_phi : (ng < 512 ? k_phi : v_out);
        int nl = ng & 255;
        float bias = (float)pbuf[(ng < 256 ? 0 : (ng < 512 ? 256 : 512)) + nl];
#pragma unroll
        for (int mf = 0; mf < 2; ++mf)
#pragma unroll
            for (int r = 0; r < 4; ++r) {
                int m = rb + mf * 16 + quad * 4 + r;
                float val = acc[mf][s][r] + bias;
                if (ng < 512) val = phi_f(val);
                dst[(size_t)m * 256 + nl] = (bf16_t)val;
            }
    }
}

// ------------------------------------------------- K2: KV state reduction
__global__ __launch_bounds__(256) void k_kvsum(
    const bf16_t* __restrict__ k_phi, const bf16_t* __restrict__ v_in,
    float* __restrict__ kvbuf) {
    const int bid = blockIdx.x;
    const int bh = bid >> 6, ck = bid & 63;
    const int b = bh >> 3, h = bh & 7;
    const int tid = threadIdx.x;
    __shared__ float ks[32][33], vs[32][33];
    const size_t base = ((size_t)b * L_SEQ + ck * 256) * 256 + h * 32;
    const int row = tid >> 3, c4 = (tid & 7) * 4;
    const int d = row, e4 = c4;
    float acc[4] = {}, ksacc = 0.f;
    for (int it = 0; it < 8; ++it) {
        bf16x4 kk4 = *(const bf16x4*)&k_phi[base + (size_t)(it * 32 + row) * 256 + c4];
        bf16x4 vv4 = *(const bf16x4*)&v_in[base + (size_t)(it * 32 + row) * 256 + c4];
#pragma unroll
        for (int j = 0; j < 4; ++j) { ks[row][c4 + j] = (float)kk4[j]; vs[row][c4 + j] = (float)vv4[j]; }
        __syncthreads();
#pragma unroll
        for (int ii = 0; ii < 32; ++ii) {
            float kd = ks[ii][d];
            ksacc += kd;
#pragma unroll
            for (int j = 0; j < 4; ++j) acc[j] += kd * vs[ii][e4 + j];
        }
        __syncthreads();
    }
    float* kvdst = kvbuf + (size_t)bh * 1056;
#pragma unroll
    for (int j = 0; j < 4; ++j) atomicAdd(&kvdst[d * 32 + e4 + j], acc[j]);
    if ((tid & 7) == 0) atomicAdd(&kvdst[1024 + d], ksacc);
}

// ------------------------------------------------- K3: apply attention
__global__ __launch_bounds__(256) void k_apply(
    const bf16_t* __restrict__ q_phi, const float* __restrict__ kvbuf,
    bf16_t* __restrict__ attn) {
    const int bid = blockIdx.x;
    const int bh = bid >> 6, ck = bid & 63;
    const int b = bh >> 3, h = bh & 7;
    const int tid = threadIdx.x;
    __shared__ float kv[32][33];
    __shared__ float ksumS[32];
    __shared__ float qs[32][33];
    const float* kvsrc = kvbuf + (size_t)bh * 1056;
    for (int idx = tid; idx < 1024; idx += 256) kv[idx >> 5][idx & 31] = kvsrc[idx];
    if (tid < 32) ksumS[tid] = kvsrc[1024 + tid];
    __syncthreads();
    const size_t base = ((size_t)b * L_SEQ + ck * 256) * 256 + h * 32;
    const int row = tid >> 3, c4 = (tid & 7) * 4;
    for (int it = 0; it < 8; ++it) {
        bf16x4 q4 = *(const bf16x4*)&q_phi[base + (size_t)(it * 32 + row) * 256 + c4];
#pragma unroll
        for (int j = 0; j < 4; ++j) qs[row][c4 + j] = (float)q4[j];
        __syncthreads();
        float num[4] = {}, den = 0.f;
#pragma unroll
        for (int dd = 0; dd < 32; ++dd) {
            float q = qs[row][dd];
            den += q * ksumS[dd];
#pragma unroll
            for (int j = 0; j < 4; ++j) num[j] += q * kv[dd][c4 + j];
        }
        float inv = 1.f / (den + 1e-6f);
        bf16x4 o;
#pragma unroll
        for (int j = 0; j < 4; ++j) o[j] = (bf16_t)(num[j] * inv);
        *(bf16x4*)&attn[base + (size_t)(it * 32 + row) * 256 + c4] = o;
        __syncthreads();
    }
}

// ------------------------------------------------- K4: @Wo + x residual + LN1
// grid 1024, M=64, full N=256. No LDS, no barriers; B from fragment-major global.
__global__ __launch_bounds__(256, 3) void k_wo_ln1(
    const bf16_t* __restrict__ attn, const bf16_t* __restrict__ Wo_f,
    const bf16_t* __restrict__ pbuf, const void* __restrict__ xraw,
    const int* __restrict__ flag, bf16_t* __restrict__ x1) {
    const int f = *flag;
    const int mt = blockIdx.x;
    const int tid = threadIdx.x, wave = tid >> 6, lane = tid & 63;
    const int l15 = lane & 15, quad = lane >> 4, q8 = quad * 8;
    const int m0 = mt * 64;
    const int mrow = m0 + wave * 16 + l15;
    f32x4 acc[16] = {};
    for (int kk = 0; kk < 8; ++kk) {
        bf16x8 a = *(const bf16x8*)&attn[(size_t)mrow * 256 + kk * 32 + q8];
#pragma unroll
        for (int s = 0; s < 16; ++s) {
            bf16x8 b = ld_frag(Wo_f, s, kk, 8, lane);
            acc[s] = __builtin_amdgcn_mfma_f32_16x16x32_bf16(a, b, acc[s], 0, 0, 0);
        }
    }
    float s1[4] = {}, s2[4] = {};
#pragma unroll
    for (int s = 0; s < 16; ++s) {
        int n = s * 16 + l15;
        float bias = (float)pbuf[768 + n];
#pragma unroll
        for (int r = 0; r < 4; ++r) {
            int m = m0 + wave * 16 + quad * 4 + r;
            float val = acc[s][r] + bias + ld_any(xraw, (size_t)m * 256 + n, f);
            acc[s][r] = val;
            s1[r] += val; s2[r] += val * val;
        }
    }
#pragma unroll
    for (int r = 0; r < 4; ++r) {
        float ts = quad_sum(s1[r]), ts2 = quad_sum(s2[r]);
        float mu = ts * (1.f / 256.f);
        float rs = rsqrtf(ts2 * (1.f / 256.f) - mu * mu + 1e-5f);
        s1[r] = mu; s2[r] = rs;
    }
#pragma unroll
    for (int s = 0; s < 16; ++s) {
        int n = s * 16 + l15;
        float gn = (float)pbuf[2304 + n], bn = (float)pbuf[2560 + n];
#pragma unroll
        for (int r = 0; r < 4; ++r) {
            int m = m0 + wave * 16 + quad * 4 + r;
            x1[(size_t)m * 256 + n] = (bf16_t)((acc[s][r] - s1[r]) * s2[r] * gn + bn);
        }
    }
}

// ------------------------------------------------- K5: fused FFN + LN2
// grid 512, M=128 (wave owns 2 m-frags). B from fragment-major global, h
// round-trip through wave-private LDS. NO __syncthreads anywhere.
__global__ __launch_bounds__(256, 2) void k_ff_ln2(
    const bf16_t* __restrict__ x1, const bf16_t* __restrict__ W1_f,
    const bf16_t* __restrict__ W2_f, const bf16_t* __restrict__ pbuf,
    const int* __restrict__ flag, void* __restrict__ out) {
    const int f32o = *flag;
    const int mt = blockIdx.x;
    const int tid = threadIdx.x, wave = tid >> 6, lane = tid & 63;
    const int l15 = lane & 15, quad = lane >> 4, q8 = quad * 8;
    __shared__ bf16_t hs[4][32][72];
    const int m0 = mt * 128;
    const int rb = m0 + wave * 32;
    f32x4 acc[2][16] = {};
    for (int ch = 0; ch < 16; ++ch) {
        // step a: h[32][64] = relu(x1_rows @ W1_chunk + b1)
        f32x4 hacc[2][4] = {};
        for (int kk = 0; kk < 8; ++kk) {
            bf16x8 a0 = *(const bf16x8*)&x1[(size_t)(rb + l15) * 256 + kk * 32 + q8];
            bf16x8 a1 = *(const bf16x8*)&x1[(size_t)(rb + 16 + l15) * 256 + kk * 32 + q8];
#pragma unroll
            for (int s = 0; s < 4; ++s) {
                bf16x8 b = ld_frag(W1_f, ch * 4 + s, kk, 8, lane);
                hacc[0][s] = __builtin_amdgcn_mfma_f32_16x16x32_bf16(a0, b, hacc[0][s], 0, 0, 0);
                hacc[1][s] = __builtin_amdgcn_mfma_f32_16x16x32_bf16(a1, b, hacc[1][s], 0, 0, 0);
            }
        }
#pragma unroll
        for (int s = 0; s < 4; ++s) {
            float bias = (float)pbuf[1024 + ch * 64 + s * 16 + l15];
#pragma unroll
            for (int mf = 0; mf < 2; ++mf)
#pragma unroll
                for (int r = 0; r < 4; ++r) {
                    float val = hacc[mf][s][r] + bias;
                    hs[wave][mf * 16 + quad * 4 + r][s * 16 + l15] = (bf16_t)(val > 0.f ? val : 0.f);
                }
        }
        // wave-local C->A layout round-trip (in-order per-wave DS pipe; no barrier)
        bf16x8 a2[2][2];
#pragma unroll
        for (int mf = 0; mf < 2; ++mf) {
            a2[mf][0] = *(const bf16x8*)&hs[wave][mf * 16 + l15][q8];
            a2[mf][1] = *(const bf16x8*)&hs[wave][mf * 16 + l15][32 + q8];
        }
        // step b: acc += h @ W2_chunk
#pragma unroll
        for (int s = 0; s < 16; ++s) {
#pragma unroll
            for (int j = 0; j < 2; ++j) {
                bf16x8 b = ld_frag(W2_f, s, ch * 2 + j, 32, lane);
                acc[0][s] = __builtin_amdgcn_mfma_f32_16x16x32_bf16(a2[0][j], b, acc[0][s], 0, 0, 0);
                acc[1][s] = __builtin_amdgcn_mfma_f32_16x16x32_bf16(a2[1][j], b, acc[1][s], 0, 0, 0);
            }
        }
    }
    // epilogue: + b2 + x1 residual, LN2, dual-dtype store
#pragma unroll
    for (int mf = 0; mf < 2; ++mf) {
        float s1[4] = {}, s2[4] = {};
#pragma unroll
        for (int s = 0; s < 16; ++s) {
            int n = s * 16 + l15;
            float bias = (float)pbuf[2048 + n];
#pragma unroll
            for (int r = 0; r < 4; ++r) {
                int m = rb + mf * 16 + quad * 4 + r;
                float val = acc[mf][s][r] + bias + (float)x1[(size_t)m * 256 + n];
                acc[mf][s][r] = val;
                s1[r] += val; s2[r] += val * val;
            }
        }
#pragma unroll
        for (int r = 0; r < 4; ++r) {
            float ts = quad_sum(s1[r]), ts2 = quad_sum(s2[r]);
            float mu = ts * (1.f / 256.f);
            float rs = rsqrtf(ts2 * (1.f / 256.f) - mu * mu + 1e-5f);
            s1[r] = mu; s2[r] = rs;
        }
#pragma unroll
        for (int s = 0; s < 16; ++s) {
            int n = s * 16 + l15;
            float gn = (float)pbuf[2816 + n], bn = (float)pbuf[3072 + n];
#pragma unroll
            for (int r = 0; r < 4; ++r) {
                int m = rb + mf * 16 + quad * 4 + r;
                float val = (acc[mf][s][r] - s1[r]) * s2[r] * gn + bn;
                if (f32o) ((float*)out)[(size_t)m * 256 + n] = val;
                else      ((bf16_t*)out)[(size_t)m * 256 + n] = (bf16_t)val;
            }
        }
    }
}

// ------------------------------------------------- launch
extern "C" void kernel_launch(void* const* d_in, const int* in_sizes, int n_in,
                              void* d_out, int out_size, void* d_ws, size_t ws_size,
                              hipStream_t stream) {
    char* ws = (char*)d_ws;
    int*    flag   = (int*)ws;                              // 4 B (256 reserved)
    bf16_t* xbf    = (bf16_t*)(ws + 256);                   // 16.7M elems
    bf16_t* Wqkv_f = (bf16_t*)(ws + 33554688);              // 196608
    bf16_t* Wo_f   = (bf16_t*)(ws + 33947904);              // 65536
    bf16_t* W1_f   = (bf16_t*)(ws + 34078976);              // 262144
    bf16_t* W2_f   = (bf16_t*)(ws + 34603264);              // 262144
    bf16_t* pbuf   = (bf16_t*)(ws + 35127552);              // 3328
    float*  kvbuf  = (float*)(ws + 35134208);               // 33792 f32
    bf16_t* bufQ   = (bf16_t*)(ws + 35269376);              // 16.7M elems
    bf16_t* bufK   = bufQ + (size_t)NTOK * 256;
    bf16_t* bufV   = bufK + (size_t)NTOK * 256;
    bf16_t* bufAttn = bufK;   // K dead after k_kvsum
    bf16_t* bufX1   = bufQ;   // Q dead after k_apply

    k_detect<<<1, 256, 0, stream>>>(d_in[0], flag);
    k_convert<<<16384, 256, 0, stream>>>(d_in[0], flag, xbf);
    k_prep<<<3217, 256, 0, stream>>>(d_in[1], d_in[3], d_in[5], d_in[7],
                                     d_in[9], d_in[11],
                                     d_in[2], d_in[4], d_in[6], d_in[8],
                                     d_in[10], d_in[12],
                                     d_in[13], d_in[14], d_in[15], d_in[16],
                                     flag, Wqkv_f, Wo_f, W1_f, W2_f, pbuf, kvbuf);
    k_qkv<<<dim3(512, 6), 256, 0, stream>>>(xbf, Wqkv_f, pbuf, bufQ, bufK, bufV);
    k_kvsum<<<2048, 256, 0, stream>>>(bufK, bufV, kvbuf);
    k_apply<<<2048, 256, 0, stream>>>(bufQ, kvbuf, bufAttn);
    k_wo_ln1<<<1024, 256, 0, stream>>>(bufAttn, Wo_f, pbuf, d_in[0], flag, bufX1);
    k_ff_ln2<<<512, 256, 0, stream>>>(bufX1, W1_f, W2_f, pbuf, flag, d_out);
}